// Round 1
// baseline (105208.093 us; speedup 1.0000x reference)
//
#include <hip/hip_runtime.h>
#include <cmath>

#define H_DIM 512
#define GATES 2048
#define SEQ   1024
#define NB    64

// ---------------- concat z = [x | w] : [65536][102] ----------------
__global__ void concat_xw(const float* __restrict__ x, const float* __restrict__ w,
                          float* __restrict__ z, int total) {
    int idx = blockIdx.x * blockDim.x + threadIdx.x;
    if (idx >= total) return;
    int m = idx / 102;
    int f = idx - m * 102;
    z[idx] = (f < 51) ? x[m * 51 + f] : w[m * 51 + (f - 51)];
}

// ------ W_hh [2048][512] -> Wt4 [k=512][h=512][gate=4] (float4 per (k,h)) ------
__global__ void interleave_whh(const float* __restrict__ W, float* __restrict__ Wt4) {
    int idx = blockIdx.x * blockDim.x + threadIdx.x;
    if (idx >= H_DIM * H_DIM * 4) return;
    int gate = idx & 3;
    int h    = (idx >> 2) & (H_DIM - 1);
    int k    = idx >> 11;
    Wt4[idx] = W[(gate * H_DIM + h) * H_DIM + k];
}

// ---------------- SGEMM: C[m][n] = sum_k A_row(m)[k]*B[n][k] (+b1[n]+b2[n]) ----------------
// A logical rows m in [0,Mp): physical row = (m>>lshift)*1024 + t0 + (m & (Lseg-1))
#define BM 128
#define BN 128
#define BK 8
#define TM 8
#define TN 8

__global__ __launch_bounds__(256) void sgemm_bias(
    const float* __restrict__ A, const float* __restrict__ B, float* __restrict__ C,
    int Mp, int Ncols, int K, int lda, int ldc, int lshift, int t0,
    const float* __restrict__ b1, const float* __restrict__ b2)
{
    __shared__ float As[BK][BM];
    __shared__ float Bs[BK][BN];
    int tid = threadIdx.x;
    int m0 = blockIdx.y * BM;
    int n0 = blockIdx.x * BN;
    int tx = tid & 15, ty = tid >> 4;
    int lrow = tid >> 1;
    int lk4  = (tid & 1) * 4;
    float acc[TM][TN] = {};

    for (int k0 = 0; k0 < K; k0 += BK) {
        // A tile -> As[k][m]
        {
            int m = m0 + lrow;
            const float* ap = nullptr;
            if (m < Mp) {
                int n = m >> lshift;
                int r = m & ((1 << lshift) - 1);
                long arow = (long)n * SEQ + t0 + r;
                ap = A + arow * (long)lda;
            }
            #pragma unroll
            for (int j = 0; j < 4; ++j) {
                int k = k0 + lk4 + j;
                As[lk4 + j][lrow] = (ap != nullptr && k < K) ? ap[k] : 0.0f;
            }
        }
        // B tile -> Bs[k][n]
        {
            int nn = n0 + lrow;
            const float* bp = (nn < Ncols) ? (B + (long)nn * K) : nullptr;
            #pragma unroll
            for (int j = 0; j < 4; ++j) {
                int k = k0 + lk4 + j;
                Bs[lk4 + j][lrow] = (bp != nullptr && k < K) ? bp[k] : 0.0f;
            }
        }
        __syncthreads();
        #pragma unroll
        for (int kk = 0; kk < BK; ++kk) {
            float a[TM], b[TN];
            *(float4*)&a[0] = *(const float4*)&As[kk][ty * TM];
            *(float4*)&a[4] = *(const float4*)&As[kk][ty * TM + 4];
            *(float4*)&b[0] = *(const float4*)&Bs[kk][tx * TN];
            *(float4*)&b[4] = *(const float4*)&Bs[kk][tx * TN + 4];
            #pragma unroll
            for (int i = 0; i < TM; ++i)
                #pragma unroll
                for (int j = 0; j < TN; ++j)
                    acc[i][j] += a[i] * b[j];
        }
        __syncthreads();
    }
    #pragma unroll
    for (int i = 0; i < TM; ++i) {
        int m = m0 + ty * TM + i;
        if (m >= Mp) continue;
        float* crow = C + (long)m * ldc;
        #pragma unroll
        for (int j = 0; j < TN; ++j) {
            int nn = n0 + tx * TN + j;
            if (nn < Ncols) {
                float v = acc[i][j];
                if (b1) v += b1[nn];
                if (b2) v += b2[nn];
                crow[nn] = v;
            }
        }
    }
}

// ---------------- LSTM recurrence: one block per batch ----------------
__device__ __forceinline__ float sigmoidf_(float v) { return 1.0f / (1.0f + __expf(-v)); }

__global__ __launch_bounds__(512) void lstm_rec(
    const float* __restrict__ G,    // [NB][Lseg][2048] gate preacts (x_proj + biases)
    const float* __restrict__ Wt4,  // [512][512] float4 {i,f,g,o}
    float* __restrict__ Hs,         // [NB][1024][512]
    float* __restrict__ carry_h, float* __restrict__ carry_c,
    int t0, int Lseg)
{
    int n = blockIdx.x;
    int tid = threadIdx.x;
    __shared__ float h[H_DIM];
    float c;
    if (t0 == 0) { h[tid] = 0.0f; c = 0.0f; }
    else         { h[tid] = carry_h[n * H_DIM + tid]; c = carry_c[n * H_DIM + tid]; }
    __syncthreads();

    const float* gb  = G + (size_t)n * Lseg * GATES;
    float* hsb = Hs + ((size_t)n * SEQ + t0) * H_DIM;
    const float4* wp = reinterpret_cast<const float4*>(Wt4) + tid;

    for (int t = 0; t < Lseg; ++t) {
        const float* gt = gb + (size_t)t * GATES;
        float ai = gt[tid];
        float af = gt[tid + 512];
        float ag = gt[tid + 1024];
        float ao = gt[tid + 1536];
        #pragma unroll 4
        for (int k = 0; k < H_DIM; k += 4) {
            float4 hv = *reinterpret_cast<const float4*>(&h[k]);
            float4 w0 = wp[(k + 0) * H_DIM];
            float4 w1 = wp[(k + 1) * H_DIM];
            float4 w2 = wp[(k + 2) * H_DIM];
            float4 w3 = wp[(k + 3) * H_DIM];
            ai += w0.x * hv.x + w1.x * hv.y + w2.x * hv.z + w3.x * hv.w;
            af += w0.y * hv.x + w1.y * hv.y + w2.y * hv.z + w3.y * hv.w;
            ag += w0.z * hv.x + w1.z * hv.y + w2.z * hv.z + w3.z * hv.w;
            ao += w0.w * hv.x + w1.w * hv.y + w2.w * hv.z + w3.w * hv.w;
        }
        float ig = sigmoidf_(ai);
        float fg = sigmoidf_(af);
        float gg = tanhf(ag);
        float og = sigmoidf_(ao);
        c = fg * c + ig * gg;
        float hn = og * tanhf(c);
        __syncthreads();          // everyone done reading old h
        h[tid] = hn;
        hsb[(size_t)t * H_DIM + tid] = hn;
        __syncthreads();          // new h visible
    }
    carry_h[n * H_DIM + tid] = h[tid];
    carry_c[n * H_DIM + tid] = c;
}

// ---------------- host ----------------
extern "C" void kernel_launch(void* const* d_in, const int* in_sizes, int n_in,
                              void* d_out, int out_size, void* d_ws, size_t ws_size,
                              hipStream_t stream)
{
    const float* x     = (const float*)d_in[0];
    const float* w_in  = (const float*)d_in[1];
    const float* W_ih[3] = { (const float*)d_in[2],  (const float*)d_in[6],  (const float*)d_in[10] };
    const float* W_hh[3] = { (const float*)d_in[3],  (const float*)d_in[7],  (const float*)d_in[11] };
    const float* b_ih[3] = { (const float*)d_in[4],  (const float*)d_in[8],  (const float*)d_in[12] };
    const float* b_hh[3] = { (const float*)d_in[5],  (const float*)d_in[9],  (const float*)d_in[13] };
    const float* W_lin = (const float*)d_in[14];
    const float* b_lin = (const float*)d_in[15];
    float* out = (float*)d_out;

    float* ws = (float*)d_ws;
    size_t off = 0;
    const int M = NB * SEQ;           // 65536
    float* z    = ws + off; off += (size_t)M * 102;          // 6,684,672
    float* Wt4[3];
    for (int l = 0; l < 3; ++l) { Wt4[l] = ws + off; off += (size_t)H_DIM * H_DIM * 4; }
    float* Hs   = ws + off; off += (size_t)M * H_DIM;        // 33,554,432
    float* ch   = ws + off; off += (size_t)NB * H_DIM;
    float* cc   = ws + off; off += (size_t)NB * H_DIM;
    float* G    = ws + off;

    size_t ws_floats = ws_size / 4;
    size_t avail = (ws_floats > off) ? (ws_floats - off) : 0;
    int Lseg = SEQ;
    while (Lseg > 1 && (size_t)NB * GATES * Lseg > avail) Lseg >>= 1;
    int nseg = SEQ / Lseg;
    int lshift = 0; { int t = Lseg; while (t > 1) { t >>= 1; ++lshift; } }

    // concat
    {
        int total = M * 102;
        concat_xw<<<(total + 255) / 256, 256, 0, stream>>>(x, w_in, z, total);
    }
    // weight interleave-transposes
    for (int l = 0; l < 3; ++l) {
        int total = H_DIM * H_DIM * 4;
        interleave_whh<<<(total + 255) / 256, 256, 0, stream>>>(W_hh[l], Wt4[l]);
    }

    for (int l = 0; l < 3; ++l) {
        const float* A = (l == 0) ? z : Hs;
        int K   = (l == 0) ? 102 : H_DIM;
        int lda = K;
        for (int s = 0; s < nseg; ++s) {
            int t0 = s * Lseg;
            int Mp = NB * Lseg;
            dim3 grid((GATES + BN - 1) / BN, (Mp + BM - 1) / BM);
            sgemm_bias<<<grid, 256, 0, stream>>>(A, W_ih[l], G, Mp, GATES, K, lda, GATES,
                                                 lshift, t0, b_ih[l], b_hh[l]);
            lstm_rec<<<NB, 512, 0, stream>>>(G, Wt4[l], Hs, ch, cc, t0, Lseg);
        }
    }
    // final linear: out = Hs @ W_lin^T + b_lin
    {
        dim3 grid((51 + BN - 1) / BN, (M + BM - 1) / BM);
        sgemm_bias<<<grid, 256, 0, stream>>>(Hs, W_lin, out, M, 51, H_DIM, H_DIM, 51,
                                             10, 0, b_lin, nullptr);
    }
}